// Round 1
// baseline (187.488 us; speedup 1.0000x reference)
//
#include <hip/hip_runtime.h>
#include <cstdint>

#define NN 2048
#define EIN 32768
#define ETOT (EIN + NN)   // 34816
#define B1 1024

// ---------------------------------------------------------------------------
// Kernel 1: single block. CSR build + degree-sorted perm + 10 GAT layers
// entirely in LDS, then q/k/v projections + per-head k min/max.
// ---------------------------------------------------------------------------
__global__ __launch_bounds__(1024) void k_gat(
    const float* __restrict__ x, const int* __restrict__ ei,
    const float* __restrict__ gW0, const float* __restrict__ gW,
    const float* __restrict__ atts, const float* __restrict__ attd,
    const float* __restrict__ gbias,
    const float* __restrict__ Wq, const float* __restrict__ bq,
    const float* __restrict__ Wk, const float* __restrict__ bk,
    const float* __restrict__ Wv, const float* __restrict__ bv,
    float* __restrict__ qh, float* __restrict__ kh, float* __restrict__ vh,
    float* __restrict__ kmm,
    int* __restrict__ g_offs, unsigned short* __restrict__ g_srcs,
    int* __restrict__ g_perm)
{
    __shared__ float4 hh[NN];                 // (hW0,hW1,hW2, a_src) then (h0,h1,h2,0)
    __shared__ unsigned short srcs[ETOT];     // CSR src lists (node ids < 65536)
    __shared__ int offs[NN + 1];
    __shared__ int aux[NN];                   // count -> cursor -> perm
    __shared__ int hist[128];
    __shared__ int redI[16];
    __shared__ float redF[6][16];

    const int tid  = threadIdx.x;
    const int lane = tid & 63;
    const int wid  = tid >> 6;

    // init counts and h0 = [x | 0,0] (pad cols multiply zero weight rows)
    for (int n = tid; n < NN; n += B1) {
        aux[n] = 0;
        hh[n] = make_float4(x[3*n], x[3*n+1], x[3*n+2], 0.f);
    }
    __syncthreads();

    // count incoming edges per dst (self loops appended)
    for (int e = tid; e < ETOT; e += B1) {
        int d = (e < EIN) ? ei[EIN + e] : (e - EIN);
        atomicAdd(&aux[d], 1);
    }
    __syncthreads();

    // exclusive scan of 2048 counts -> offs
    {
        int c0 = aux[2*tid], c1 = aux[2*tid + 1];
        int pairv = c0 + c1;
        int v = pairv;
        #pragma unroll
        for (int d = 1; d < 64; d <<= 1) {
            int u = __shfl_up(v, d);
            if (lane >= d) v += u;
        }
        if (lane == 63) redI[wid] = v;
        __syncthreads();
        if (wid == 0 && lane < 16) {
            int t = redI[lane];
            #pragma unroll
            for (int d = 1; d < 16; d <<= 1) {
                int u = __shfl_up(t, d);
                if (lane >= d) t += u;
            }
            redI[lane] = t;
        }
        __syncthreads();
        int base = (wid ? redI[wid - 1] : 0) + (v - pairv);
        offs[2*tid]     = base;
        offs[2*tid + 1] = base + c0;
        if (tid == B1 - 1) offs[NN] = base + pairv;
    }
    __syncthreads();

    // cursor = offs, then scatter src ids grouped by dst
    for (int n = tid; n < NN; n += B1) aux[n] = offs[n];
    __syncthreads();
    for (int e = tid; e < ETOT; e += B1) {
        int s = (e < EIN) ? ei[e]       : (e - EIN);
        int d = (e < EIN) ? ei[EIN + e] : (e - EIN);
        int p = atomicAdd(&aux[d], 1);
        srcs[p] = (unsigned short)s;
    }
    __syncthreads();

    // degree-sorted permutation (counting sort) to kill wave divergence
    if (tid < 128) hist[tid] = 0;
    __syncthreads();
    for (int n = tid; n < NN; n += B1) {
        int deg = offs[n+1] - offs[n];
        atomicAdd(&hist[min(deg, 127)], 1);
    }
    __syncthreads();
    if (tid == 0) {
        int acc = 0;
        for (int b = 0; b < 128; b++) { int c = hist[b]; hist[b] = acc; acc += c; }
    }
    __syncthreads();
    for (int n = tid; n < NN; n += B1) {
        int deg = offs[n+1] - offs[n];
        int p = atomicAdd(&hist[min(deg, 127)], 1);
        aux[p] = n;                      // perm
    }
    __syncthreads();

    // dump CSR + perm to global for kernel 3
    for (int n = tid; n <= NN; n += B1) g_offs[n] = offs[n];
    for (int e = tid; e < ETOT; e += B1) g_srcs[e] = srcs[e];
    for (int n = tid; n < NN; n += B1) g_perm[n] = aux[n];

    const int myn0 = aux[tid];
    const int myn1 = aux[tid + B1];

    // ------------------------- 10 GAT layers -------------------------
    for (int l = 0; l < 10; l++) {
        const float* W = (l == 0) ? gW0 : (gW + (l - 1) * 9);
        float w00=W[0],w01=W[1],w02=W[2],w10=W[3],w11=W[4],w12=W[5],w20=W[6],w21=W[7],w22=W[8];
        float s0=atts[l*3],s1=atts[l*3+1],s2=atts[l*3+2];
        float d0=attd[l*3],d1=attd[l*3+1],d2=attd[l*3+2];
        float ad_[2];
        // node pass: h -> (hW, a_src) in place; a_dst kept in regs
        #pragma unroll
        for (int i = 0; i < 2; i++) {
            int n = i ? myn1 : myn0;
            float4 hv = hh[n];
            float p0 = hv.x*w00 + hv.y*w10 + hv.z*w20;
            float p1 = hv.x*w01 + hv.y*w11 + hv.z*w21;
            float p2 = hv.x*w02 + hv.y*w12 + hv.z*w22;
            float as = p0*s0 + p1*s1 + p2*s2;
            ad_[i]   = p0*d0 + p1*d1 + p2*d2;
            hh[n] = make_float4(p0, p1, p2, as);
        }
        __syncthreads();
        // edge pass: per-dst online softmax (branchless rescale)
        float hn[2][3];
        #pragma unroll
        for (int i = 0; i < 2; i++) {
            int n = i ? myn1 : myn0;
            float m = -1e30f, se = 0.f, a0 = 0.f, a1 = 0.f, a2 = 0.f;
            int pe = offs[n+1];
            for (int p = offs[n]; p < pe; p++) {
                int sidx = srcs[p];
                float4 hs = hh[sidx];
                float lg = hs.w + ad_[i];
                lg = (lg > 0.f) ? lg : 0.2f * lg;      // leaky_relu 0.2
                float nm = fmaxf(m, lg);
                float r   = __expf(m - nm);
                float wgt = __expf(lg - nm);
                se = se*r + wgt;
                a0 = a0*r + wgt*hs.x;
                a1 = a1*r + wgt*hs.y;
                a2 = a2*r + wgt*hs.z;
                m = nm;
            }
            float inv = 1.f / (se + 1e-16f);
            float o0 = a0*inv + gbias[l*3+0];
            float o1 = a1*inv + gbias[l*3+1];
            float o2 = a2*inv + gbias[l*3+2];
            if (l < 9) { o0 = fmaxf(o0,0.f); o1 = fmaxf(o1,0.f); o2 = fmaxf(o2,0.f); }
            hn[i][0]=o0; hn[i][1]=o1; hn[i][2]=o2;
        }
        __syncthreads();
        hh[myn0] = make_float4(hn[0][0], hn[0][1], hn[0][2], 0.f);
        hh[myn1] = make_float4(hn[1][0], hn[1][1], hn[1][2], 0.f);
        __syncthreads();
    }

    // q/k/v projections (head-major) + per-head k min/max
    float kmx[3] = {-1e30f,-1e30f,-1e30f}, kmn[3] = {1e30f,1e30f,1e30f};
    #pragma unroll
    for (int i = 0; i < 2; i++) {
        int n = tid + i*B1;
        float4 g = hh[n];
        #pragma unroll
        for (int c = 0; c < 3; c++) {
            float qv = g.x*Wq[c] + g.y*Wq[3+c] + g.z*Wq[6+c] + bq[c];
            float kv = g.x*Wk[c] + g.y*Wk[3+c] + g.z*Wk[6+c] + bk[c];
            float vv = g.x*Wv[c] + g.y*Wv[3+c] + g.z*Wv[6+c] + bv[c];
            qh[c*NN+n] = qv; kh[c*NN+n] = kv; vh[c*NN+n] = vv;
            kmx[c] = fmaxf(kmx[c], kv); kmn[c] = fminf(kmn[c], kv);
        }
    }
    #pragma unroll
    for (int c = 0; c < 3; c++) {
        float a = kmx[c], b = kmn[c];
        #pragma unroll
        for (int d = 32; d; d >>= 1) {
            a = fmaxf(a, __shfl_xor(a, d));
            b = fminf(b, __shfl_xor(b, d));
        }
        if (lane == 0) { redF[c][wid] = a; redF[3+c][wid] = b; }
    }
    __syncthreads();
    if (tid == 0) {
        #pragma unroll
        for (int c = 0; c < 3; c++) {
            float a = redF[c][0], b = redF[3+c][0];
            for (int wv = 1; wv < 16; wv++) {
                a = fmaxf(a, redF[c][wv]); b = fminf(b, redF[3+c][wv]);
            }
            kmm[c] = a; kmm[3+c] = b;
        }
    }
}

// ---------------------------------------------------------------------------
// Kernel 2: MHA context. One wave per (head,row): softmax over 2048 cols.
// scores[h,n,m] = q[h,n]*k[h,m] (head_dim=1, scale=1). Row max is
// q>=0 ? q*kmax : q*kmin (precomputed).
// ---------------------------------------------------------------------------
__global__ __launch_bounds__(256) void k_mha(
    const float* __restrict__ qh, const float* __restrict__ kh,
    const float* __restrict__ vh, const float* __restrict__ kmm,
    float* __restrict__ ctx)
{
    int gw   = (blockIdx.x * 256 + threadIdx.x) >> 6;   // 6144 waves
    int lane = threadIdx.x & 63;
    int h = gw >> 11, n = gw & (NN - 1);
    float q = qh[h*NN + n];
    float M = (q >= 0.f) ? q * kmm[h] : q * kmm[3 + h];
    float se = 0.f, sv = 0.f;
    const float* kp = kh + h*NN;
    const float* vp = vh + h*NN;
    for (int m = lane; m < NN; m += 64) {
        float w = __expf(q * kp[m] - M);
        se += w; sv += w * vp[m];
    }
    #pragma unroll
    for (int d = 32; d; d >>= 1) { se += __shfl_xor(se, d); sv += __shfl_xor(sv, d); }
    if (lane == 0) ctx[h*NN + n] = sv / se;
}

// ---------------------------------------------------------------------------
// Kernel 2b: res = ctx^T @ Wo + bo, then tq/tk/tv/skip projections to ws.
// ---------------------------------------------------------------------------
__global__ __launch_bounds__(256) void k_post(
    const float* __restrict__ ctx,
    const float* __restrict__ Wo, const float* __restrict__ bo,
    const float* __restrict__ tWq, const float* __restrict__ tbq,
    const float* __restrict__ tWk, const float* __restrict__ tbk,
    const float* __restrict__ tWv, const float* __restrict__ tbv,
    const float* __restrict__ Wsk, const float* __restrict__ bsk,
    float* __restrict__ tq, float4* __restrict__ tkv, float* __restrict__ skip)
{
    int n = blockIdx.x * 256 + threadIdx.x;
    float c0 = ctx[n], c1 = ctx[NN + n], c2 = ctx[2*NN + n];
    float r0 = c0*Wo[0] + c1*Wo[3] + c2*Wo[6] + bo[0];
    float r1 = c0*Wo[1] + c1*Wo[4] + c2*Wo[7] + bo[1];
    float r2 = c0*Wo[2] + c1*Wo[5] + c2*Wo[8] + bo[2];

    float q0 = r0*tWq[0] + r1*tWq[3] + r2*tWq[6] + tbq[0];
    float q1 = r0*tWq[1] + r1*tWq[4] + r2*tWq[7] + tbq[1];
    float q2 = r0*tWq[2] + r1*tWq[5] + r2*tWq[8] + tbq[2];
    tq[3*n] = q0; tq[3*n+1] = q1; tq[3*n+2] = q2;

    float k0 = r0*tWk[0] + r1*tWk[3] + r2*tWk[6] + tbk[0];
    float k1 = r0*tWk[1] + r1*tWk[4] + r2*tWk[7] + tbk[1];
    float k2 = r0*tWk[2] + r1*tWk[5] + r2*tWk[8] + tbk[2];
    float v0 = r0*tWv[0] + r1*tWv[3] + r2*tWv[6] + tbv[0];
    float v1 = r0*tWv[1] + r1*tWv[4] + r2*tWv[7] + tbv[1];
    float v2 = r0*tWv[2] + r1*tWv[5] + r2*tWv[8] + tbv[2];
    tkv[2*n]   = make_float4(k0, k1, k2, v0);
    tkv[2*n+1] = make_float4(v1, v2, 0.f, 0.f);

    skip[3*n]   = r0*Wsk[0] + r1*Wsk[3] + r2*Wsk[6] + bsk[0];
    skip[3*n+1] = r0*Wsk[1] + r1*Wsk[4] + r2*Wsk[7] + bsk[1];
    skip[3*n+2] = r0*Wsk[2] + r1*Wsk[5] + r2*Wsk[8] + bsk[2];
}

// ---------------------------------------------------------------------------
// Kernel 3: TransformerConv (online segment softmax over CSR) + skip +
// per-node MLP + mask + critic value. Single block.
// ---------------------------------------------------------------------------
__global__ __launch_bounds__(1024) void k_tc(
    const float* __restrict__ tq, const float4* __restrict__ tkvG,
    const float* __restrict__ skip,
    const int* __restrict__ g_offs, const unsigned short* __restrict__ g_srcs,
    const int* __restrict__ g_perm,
    const float* __restrict__ mask,
    const float* __restrict__ W1, const float* __restrict__ b1v,
    const float* __restrict__ W2, const float* __restrict__ b2v,
    const float* __restrict__ W3, const float* __restrict__ b3v,
    const float* __restrict__ cW, const float* __restrict__ cb,
    float* __restrict__ outp)
{
    __shared__ float4 tkv[2*NN];
    __shared__ int offs[NN + 1];
    __shared__ float redS[16];
    const int tid = threadIdx.x, lane = tid & 63, wid = tid >> 6;

    for (int i = tid; i < 2*NN; i += B1) tkv[i] = tkvG[i];
    for (int i = tid; i <= NN; i += B1) offs[i] = g_offs[i];
    __syncthreads();

    float lsum = 0.f;
    #pragma unroll
    for (int i = 0; i < 2; i++) {
        int n = g_perm[tid + i*B1];
        float q0 = tq[3*n], q1 = tq[3*n+1], q2 = tq[3*n+2];
        float m = -1e30f, se = 0.f, a0 = 0.f, a1 = 0.f, a2 = 0.f;
        int pe = offs[n+1];
        for (int p = offs[n]; p < pe; p++) {
            int sidx = g_srcs[p];
            float4 A = tkv[2*sidx];
            float4 Bv = tkv[2*sidx + 1];
            float lg = (q0*A.x + q1*A.y + q2*A.z) * 0.5773502691896258f; // /sqrt(3)
            float nm = fmaxf(m, lg);
            float r   = __expf(m - nm);
            float wgt = __expf(lg - nm);
            se = se*r + wgt;
            a0 = a0*r + wgt*A.w;
            a1 = a1*r + wgt*Bv.x;
            a2 = a2*r + wgt*Bv.y;
            m = nm;
        }
        float inv = 1.f / (se + 1e-16f);
        float o0 = a0*inv + skip[3*n];
        float o1 = a1*inv + skip[3*n+1];
        float o2 = a2*inv + skip[3*n+2];

        // MLP 5->16->32->1 (pad cols 3,4 are zero -> W1 rows 3,4 unused)
        float h1[16];
        #pragma unroll
        for (int k = 0; k < 16; k++)
            h1[k] = fmaxf(o0*W1[k] + o1*W1[16+k] + o2*W1[32+k] + b1v[k], 0.f);
        float racc = b3v[0];
        #pragma unroll
        for (int j = 0; j < 32; j++) {
            float t = b2v[j];
            #pragma unroll
            for (int k = 0; k < 16; k++) t += h1[k] * W2[k*32 + j];
            racc += fmaxf(t, 0.f) * W3[j];
        }
        outp[n] = racc * mask[n];
        lsum += racc;
    }
    #pragma unroll
    for (int d = 32; d; d >>= 1) lsum += __shfl_xor(lsum, d);
    if (lane == 0) redS[wid] = lsum;
    __syncthreads();
    if (tid == 0) {
        float t = 0.f;
        for (int wv = 0; wv < 16; wv++) t += redS[wv];
        outp[NN] = cW[0] * (t / (float)NN) + cb[0];
    }
}

// ---------------------------------------------------------------------------
extern "C" void kernel_launch(void* const* d_in, const int* in_sizes, int n_in,
                              void* d_out, int out_size, void* d_ws, size_t ws_size,
                              hipStream_t stream)
{
    const float* x    = (const float*)d_in[0];
    const int*   ei   = (const int*)  d_in[1];
    const float* mask = (const float*)d_in[2];
    const float* gW0  = (const float*)d_in[3];
    const float* gW   = (const float*)d_in[4];
    const float* atts = (const float*)d_in[5];
    const float* attd = (const float*)d_in[6];
    const float* gbias= (const float*)d_in[7];
    const float* mWq = (const float*)d_in[8];  const float* mbq = (const float*)d_in[9];
    const float* mWk = (const float*)d_in[10]; const float* mbk = (const float*)d_in[11];
    const float* mWv = (const float*)d_in[12]; const float* mbv = (const float*)d_in[13];
    const float* mWo = (const float*)d_in[14]; const float* mbo = (const float*)d_in[15];
    const float* tWq = (const float*)d_in[16]; const float* tbq = (const float*)d_in[17];
    const float* tWk = (const float*)d_in[18]; const float* tbk = (const float*)d_in[19];
    const float* tWv = (const float*)d_in[20]; const float* tbv = (const float*)d_in[21];
    const float* tWs = (const float*)d_in[22]; const float* tbs = (const float*)d_in[23];
    const float* W1  = (const float*)d_in[24]; const float* b1  = (const float*)d_in[25];
    const float* W2  = (const float*)d_in[26]; const float* b2  = (const float*)d_in[27];
    const float* W3  = (const float*)d_in[28]; const float* b3  = (const float*)d_in[29];
    const float* cW  = (const float*)d_in[30]; const float* cb  = (const float*)d_in[31];

    float* ws   = (float*)d_ws;
    float* qh   = ws;
    float* kh   = ws + 6144;
    float* vh   = ws + 12288;
    float* kmm  = ws + 18432;                 // 8 floats (max0..2, min0..2)
    float* ctx  = ws + 18440;
    float* tq   = ws + 24584;
    float* skip = ws + 30728;
    float4* tkv = (float4*)(ws + 36872);      // 2048*2 float4 (16B aligned)
    int* g_offs = (int*)(ws + 53256);         // 2049 ints
    unsigned short* g_srcs = (unsigned short*)(ws + 55308); // 34816 u16
    int* g_perm = (int*)(ws + 72716);         // 2048 ints

    k_gat<<<1, 1024, 0, stream>>>(x, ei, gW0, gW, atts, attd, gbias,
                                  mWq, mbq, mWk, mbk, mWv, mbv,
                                  qh, kh, vh, kmm, g_offs, g_srcs, g_perm);
    k_mha<<<1536, 256, 0, stream>>>(qh, kh, vh, kmm, ctx);
    k_post<<<8, 256, 0, stream>>>(ctx, mWo, mbo, tWq, tbq, tWk, tbk, tWv, tbv,
                                  tWs, tbs, tq, tkv, skip);
    k_tc<<<1, 1024, 0, stream>>>(tq, tkv, skip, g_offs, g_srcs, g_perm, mask,
                                 W1, b1, W2, b2, W3, b3, cW, cb, (float*)d_out);
}

// Round 2
// 182.852 us; speedup vs baseline: 1.0254x; 1.0254x over previous
//
#include <hip/hip_runtime.h>
#include <cstdint>

#define NN   2048
#define EIN  32768
#define ETOT (EIN + NN)      // 34816
#define NB   64
#define BT   256
#define NT   (NB * BT)       // 16384
#define DPB  (NN / NB)       // 32 dsts per block
#define SCAP 6144

// ---- workspace byte offsets (16B-aligned float4 regions) ----
#define WS_BAR     0          // int[1]      (memset)
#define WS_COUNTS  4          // int[2048]   (memset)
#define WS_CURSOR  8196       // int[2048]
#define WS_RANK    16388      // int[2048]
#define WS_PERM    24580      // int[2048]
#define WS_OFFS    32772      // int[2049]
#define WS_HB0     40976      // float4[2048]
#define WS_HB1     73744      // float4[2048]
#define WS_QG      106512     // float[6144]
#define WS_KG      131088     // float[6144]
#define WS_VG      155664     // float[6144]
#define WS_KPART   180240     // float[384]
#define WS_CTX     181776     // float[6144]
#define WS_TQ4     206352     // float4[2048]
#define WS_TKV     239120     // float4[4096]
#define WS_SKIP4   304656     // float4[2048]
#define WS_VPART   337424     // float[64]
#define WS_SRCS    337680     // u16[34816]
#define WS_MEMSET_BYTES 8196

__device__ __forceinline__ void gbar(int* cnt, int target) {
    __syncthreads();
    if (threadIdx.x == 0) {
        __threadfence();
        __hip_atomic_fetch_add(cnt, 1, __ATOMIC_RELEASE, __HIP_MEMORY_SCOPE_AGENT);
        while (__hip_atomic_load(cnt, __ATOMIC_ACQUIRE, __HIP_MEMORY_SCOPE_AGENT) < target)
            __builtin_amdgcn_s_sleep(2);
        __threadfence();
    }
    __syncthreads();
}

__global__ __launch_bounds__(BT) void k_fused(
    const float* __restrict__ x, const int* __restrict__ ei,
    const float* __restrict__ maskp,
    const float* __restrict__ gW0, const float* __restrict__ gW,
    const float* __restrict__ atts, const float* __restrict__ attd,
    const float* __restrict__ gbias,
    const float* __restrict__ mWq, const float* __restrict__ mbq,
    const float* __restrict__ mWk, const float* __restrict__ mbk,
    const float* __restrict__ mWv, const float* __restrict__ mbv,
    const float* __restrict__ mWo, const float* __restrict__ mbo,
    const float* __restrict__ tWq, const float* __restrict__ tbq,
    const float* __restrict__ tWk, const float* __restrict__ tbk,
    const float* __restrict__ tWv, const float* __restrict__ tbv,
    const float* __restrict__ tWs, const float* __restrict__ tbs,
    const float* __restrict__ W1, const float* __restrict__ b1,
    const float* __restrict__ W2, const float* __restrict__ b2,
    const float* __restrict__ W3, const float* __restrict__ b3,
    const float* __restrict__ cW, const float* __restrict__ cb,
    char* __restrict__ ws, float* __restrict__ outp)
{
    __shared__ float4 hw4[NN];                 // 32KB: replicated (hW, a_src)
    __shared__ float  adst[NN];                // 8KB : replicated a_dst
    __shared__ unsigned short lsrc[SCAP];      // 12KB: this block's CSR slice
    __shared__ int   hist[128];
    __shared__ int   redi[8];
    __shared__ float redf[64];

    int*   bar    = (int*)(ws + WS_BAR);
    int*   counts = (int*)(ws + WS_COUNTS);
    int*   cursor = (int*)(ws + WS_CURSOR);
    int*   rankg  = (int*)(ws + WS_RANK);
    int*   permg  = (int*)(ws + WS_PERM);
    int*   offsg  = (int*)(ws + WS_OFFS);
    float4* hb0   = (float4*)(ws + WS_HB0);
    float4* hb1   = (float4*)(ws + WS_HB1);
    float* qg     = (float*)(ws + WS_QG);
    float* kg     = (float*)(ws + WS_KG);
    float* vg     = (float*)(ws + WS_VG);
    float* kpart  = (float*)(ws + WS_KPART);
    float* ctx    = (float*)(ws + WS_CTX);
    float4* tq4   = (float4*)(ws + WS_TQ4);
    float4* tkv   = (float4*)(ws + WS_TKV);
    float4* skip4 = (float4*)(ws + WS_SKIP4);
    float* vpart  = (float*)(ws + WS_VPART);
    unsigned short* srcsg = (unsigned short*)(ws + WS_SRCS);

    const int tid = threadIdx.x;
    const int bid = blockIdx.x;
    const int gtid = bid * BT + tid;
    const int R0 = bid * DPB;

    // ---------------- P0: h0 init + per-dst edge counts ----------------
    if (gtid < NN) {
        int n = gtid;
        hb0[n] = make_float4(x[3*n], x[3*n+1], x[3*n+2], 0.f);
    }
    for (int e = gtid; e < ETOT; e += NT) {
        int d = (e < EIN) ? ei[EIN + e] : (e - EIN);
        atomicAdd(&counts[d], 1);
    }
    gbar(bar, NB * 1);

    // ---------------- P1 (block 0): degree sort + CSR offsets ----------------
    if (bid == 0) {
        if (tid < 128) hist[tid] = 0;
        __syncthreads();
        for (int n = tid; n < NN; n += BT) {
            int deg = counts[n]; if (deg > 127) deg = 127;
            atomicAdd(&hist[deg], 1);
        }
        __syncthreads();
        if (tid < 64) {
            int a = hist[2*tid], b = hist[2*tid+1];
            int v = a + b;
            #pragma unroll
            for (int d = 1; d < 64; d <<= 1) {
                int u = __shfl_up(v, d);
                if (tid >= d) v += u;
            }
            hist[2*tid]   = v - a - b;     // exclusive bin starts
            hist[2*tid+1] = v - b;
        }
        __syncthreads();
        for (int n = tid; n < NN; n += BT) {
            int deg = counts[n]; if (deg > 127) deg = 127;
            int p = atomicAdd(&hist[deg], 1);
            permg[p] = n; rankg[n] = p;
        }
        __syncthreads();
        // exclusive scan of degrees in rank order -> offs, cursor
        int base_p = tid * 8;
        int pre[8]; int tot = 0;
        #pragma unroll
        for (int j = 0; j < 8; j++) {
            int nd = permg[base_p + j];
            pre[j] = tot; tot += counts[nd];
        }
        int lane6 = tid & 63, w = tid >> 6;
        int vi = tot;
        #pragma unroll
        for (int d = 1; d < 64; d <<= 1) {
            int u = __shfl_up(vi, d);
            if (lane6 >= d) vi += u;
        }
        if (lane6 == 63) redi[w] = vi;
        __syncthreads();
        int wbase = 0;
        for (int ww = 0; ww < w; ww++) wbase += redi[ww];
        int ex = wbase + vi - tot;
        #pragma unroll
        for (int j = 0; j < 8; j++) {
            offsg[base_p + j]  = ex + pre[j];
            cursor[base_p + j] = ex + pre[j];
        }
        if (tid == 0) offsg[NN] = ETOT;
    }
    gbar(bar, NB * 2);

    // ---------------- P2: scatter srcs grouped by dst rank ----------------
    for (int e = gtid; e < ETOT; e += NT) {
        int s = (e < EIN) ? ei[e]       : (e - EIN);
        int d = (e < EIN) ? ei[EIN + e] : (e - EIN);
        int r = rankg[d];
        int p = atomicAdd(&cursor[r], 1);
        srcsg[p] = (unsigned short)s;
    }
    gbar(bar, NB * 3);

    // stage this block's CSR slice to LDS (persists through GAT + TC)
    const int sbase = offsg[R0];
    const int slen  = offsg[R0 + DPB] - sbase;
    const bool inl  = (slen <= SCAP);
    if (inl) for (int i = tid; i < slen; i += BT) lsrc[i] = srcsg[sbase + i];

    // ---------------- 10 GAT layers ----------------
    for (int l = 0; l < 10; l++) {
        const float4* ha = (l & 1) ? hb1 : hb0;
        float4*       hn = (l & 1) ? hb0 : hb1;
        const float* W = l ? (gW + (l - 1) * 9) : gW0;
        float w00=W[0],w01=W[1],w02=W[2],w10=W[3],w11=W[4],w12=W[5],w20=W[6],w21=W[7],w22=W[8];
        float s0=atts[l*3],s1=atts[l*3+1],s2=atts[l*3+2];
        float d0=attd[l*3],d1=attd[l*3+1],d2=attd[l*3+2];
        // replicated node pass into LDS
        #pragma unroll
        for (int j = 0; j < NN / BT; j++) {
            int n = tid + j * BT;
            float4 hv = ha[n];
            float p0 = hv.x*w00 + hv.y*w10 + hv.z*w20;
            float p1 = hv.x*w01 + hv.y*w11 + hv.z*w21;
            float p2 = hv.x*w02 + hv.y*w12 + hv.z*w22;
            hw4[n]  = make_float4(p0, p1, p2, p0*s0 + p1*s1 + p2*s2);
            adst[n] = p0*d0 + p1*d1 + p2*d2;
        }
        __syncthreads();
        // edge pass: 8 lanes per owned dst, online softmax + shuffle merge
        int j = tid >> 3, sub = tid & 7;
        int r = R0 + j;
        int n = permg[r];
        int ps = offsg[r], pe = offsg[r + 1];
        float ad = adst[n];
        float m = -1e30f, se = 0.f, a0 = 0.f, a1 = 0.f, a2 = 0.f;
        for (int p = ps + sub; p < pe; p += 8) {
            int s = inl ? (int)lsrc[p - sbase] : (int)srcsg[p];
            float4 hs = hw4[s];
            float lg = hs.w + ad;
            lg = (lg > 0.f) ? lg : 0.2f * lg;
            float nm = fmaxf(m, lg);
            float rr = __expf(m - nm);
            float wg = __expf(lg - nm);
            se = se*rr + wg;
            a0 = a0*rr + wg*hs.x;
            a1 = a1*rr + wg*hs.y;
            a2 = a2*rr + wg*hs.z;
            m = nm;
        }
        #pragma unroll
        for (int d = 1; d < 8; d <<= 1) {
            float m2 = __shfl_xor(m, d), se2 = __shfl_xor(se, d);
            float q0 = __shfl_xor(a0, d), q1 = __shfl_xor(a1, d), q2 = __shfl_xor(a2, d);
            float nm = fmaxf(m, m2);
            float f1 = __expf(m - nm), f2 = __expf(m2 - nm);
            se = se*f1 + se2*f2;
            a0 = a0*f1 + q0*f2; a1 = a1*f1 + q1*f2; a2 = a2*f1 + q2*f2;
            m = nm;
        }
        if (sub == 0) {
            float inv = 1.f / (se + 1e-16f);
            float o0 = a0*inv + gbias[l*3+0];
            float o1 = a1*inv + gbias[l*3+1];
            float o2 = a2*inv + gbias[l*3+2];
            if (l < 9) { o0 = fmaxf(o0,0.f); o1 = fmaxf(o1,0.f); o2 = fmaxf(o2,0.f); }
            hn[n] = make_float4(o0, o1, o2, 0.f);
        }
        gbar(bar, NB * (4 + l));
    }

    // ---------------- QKV projections + per-block k min/max partials ----------------
    {
        float kmx[3] = {-3e38f,-3e38f,-3e38f}, kmn[3] = {3e38f,3e38f,3e38f};
        if (gtid < NN) {
            int n = gtid;
            float4 g = hb0[n];   // final h after layer 10
            #pragma unroll
            for (int c = 0; c < 3; c++) {
                float qv = g.x*mWq[c] + g.y*mWq[3+c] + g.z*mWq[6+c] + mbq[c];
                float kv = g.x*mWk[c] + g.y*mWk[3+c] + g.z*mWk[6+c] + mbk[c];
                float vv = g.x*mWv[c] + g.y*mWv[3+c] + g.z*mWv[6+c] + mbv[c];
                qg[c*NN+n] = qv; kg[c*NN+n] = kv; vg[c*NN+n] = vv;
                kmx[c] = fmaxf(kmx[c], kv); kmn[c] = fminf(kmn[c], kv);
            }
        }
        int lane = tid & 63, wid = tid >> 6;
        #pragma unroll
        for (int c = 0; c < 3; c++) {
            #pragma unroll
            for (int d = 1; d < 64; d <<= 1) {
                kmx[c] = fmaxf(kmx[c], __shfl_xor(kmx[c], d));
                kmn[c] = fminf(kmn[c], __shfl_xor(kmn[c], d));
            }
        }
        if (lane == 0) {
            #pragma unroll
            for (int c = 0; c < 3; c++) {
                redf[wid*8 + c]     = kmx[c];
                redf[wid*8 + 4 + c] = kmn[c];
            }
        }
        __syncthreads();
        if (tid < 6) {
            int c = tid % 3; bool ismax = tid < 3;
            float acc = ismax ? -3e38f : 3e38f;
            for (int w2 = 0; w2 < 4; w2++) {
                float t = redf[w2*8 + (ismax ? c : 4 + c)];
                acc = ismax ? fmaxf(acc, t) : fminf(acc, t);
            }
            kpart[bid*6 + tid] = acc;   // [0..2]=max, [3..5]=min
        }
    }
    gbar(bar, NB * 14);

    // ---------------- MHA: 2 threads per (head,row) ----------------
    {
        if (tid < 6) {
            bool ismax = tid < 3;
            float acc = ismax ? -3e38f : 3e38f;
            for (int b = 0; b < NB; b++) {
                float t = kpart[b*6 + tid];
                acc = ismax ? fmaxf(acc, t) : fminf(acc, t);
            }
            redf[tid] = acc;
        }
        __syncthreads();
        int u = gtid;
        int row = u >> 1;
        if (row < 3 * NN) {
            int h = row >> 11, n = row & (NN - 1), half = u & 1;
            float q = qg[h*NN + n];
            float M = (q >= 0.f) ? q * redf[h] : q * redf[3 + h];
            const float4* k4 = (const float4*)(kg + h*NN) + half * (NN/8);
            const float4* v4 = (const float4*)(vg + h*NN) + half * (NN/8);
            float se = 0.f, sv = 0.f;
            for (int i = 0; i < NN/8; i++) {
                float4 kk = k4[i], vv = v4[i];
                float e0 = __expf(q*kk.x - M);
                float e1 = __expf(q*kk.y - M);
                float e2 = __expf(q*kk.z - M);
                float e3 = __expf(q*kk.w - M);
                se += e0 + e1 + e2 + e3;
                sv = fmaf(e0, vv.x, fmaf(e1, vv.y, fmaf(e2, vv.z, fmaf(e3, vv.w, sv))));
            }
            se += __shfl_xor(se, 1);
            sv += __shfl_xor(sv, 1);
            if (!half) ctx[h*NN + n] = sv / se;
        }
    }
    gbar(bar, NB * 15);

    // ---------------- POST: res + TC projections + skip ----------------
    if (gtid < NN) {
        int n = gtid;
        float c0 = ctx[n], c1 = ctx[NN + n], c2 = ctx[2*NN + n];
        float r0 = c0*mWo[0] + c1*mWo[3] + c2*mWo[6] + mbo[0];
        float r1 = c0*mWo[1] + c1*mWo[4] + c2*mWo[7] + mbo[1];
        float r2 = c0*mWo[2] + c1*mWo[5] + c2*mWo[8] + mbo[2];
        float q0 = r0*tWq[0] + r1*tWq[3] + r2*tWq[6] + tbq[0];
        float q1 = r0*tWq[1] + r1*tWq[4] + r2*tWq[7] + tbq[1];
        float q2 = r0*tWq[2] + r1*tWq[5] + r2*tWq[8] + tbq[2];
        float k0 = r0*tWk[0] + r1*tWk[3] + r2*tWk[6] + tbk[0];
        float k1 = r0*tWk[1] + r1*tWk[4] + r2*tWk[7] + tbk[1];
        float k2 = r0*tWk[2] + r1*tWk[5] + r2*tWk[8] + tbk[2];
        float v0 = r0*tWv[0] + r1*tWv[3] + r2*tWv[6] + tbv[0];
        float v1 = r0*tWv[1] + r1*tWv[4] + r2*tWv[7] + tbv[1];
        float v2 = r0*tWv[2] + r1*tWv[5] + r2*tWv[8] + tbv[2];
        tq4[n]     = make_float4(q0, q1, q2, 0.f);
        tkv[2*n]   = make_float4(k0, k1, k2, v0);
        tkv[2*n+1] = make_float4(v1, v2, 0.f, 0.f);
        float s0 = r0*tWs[0] + r1*tWs[3] + r2*tWs[6] + tbs[0];
        float s1 = r0*tWs[1] + r1*tWs[4] + r2*tWs[7] + tbs[1];
        float s2 = r0*tWs[2] + r1*tWs[5] + r2*tWs[8] + tbs[2];
        skip4[n] = make_float4(s0, s1, s2, 0.f);
    }
    gbar(bar, NB * 16);

    // ---------------- TC edge pass + MLP + mask + partial sums ----------------
    {
        int j = tid >> 3, sub = tid & 7;
        int r = R0 + j;
        int n = permg[r];
        float4 qv = tq4[n];
        int ps = offsg[r], pe = offsg[r + 1];
        float m = -1e30f, se = 0.f, a0 = 0.f, a1 = 0.f, a2 = 0.f;
        for (int p = ps + sub; p < pe; p += 8) {
            int s = inl ? (int)lsrc[p - sbase] : (int)srcsg[p];
            float4 A = tkv[2*s];
            float4 B = tkv[2*s + 1];
            float lg = (qv.x*A.x + qv.y*A.y + qv.z*A.z) * 0.5773502691896258f;
            float nm = fmaxf(m, lg);
            float rr = __expf(m - nm);
            float wg = __expf(lg - nm);
            se = se*rr + wg;
            a0 = a0*rr + wg*A.w;
            a1 = a1*rr + wg*B.x;
            a2 = a2*rr + wg*B.y;
            m = nm;
        }
        #pragma unroll
        for (int d = 1; d < 8; d <<= 1) {
            float m2 = __shfl_xor(m, d), se2 = __shfl_xor(se, d);
            float q0 = __shfl_xor(a0, d), q1 = __shfl_xor(a1, d), q2 = __shfl_xor(a2, d);
            float nm = fmaxf(m, m2);
            float f1 = __expf(m - nm), f2 = __expf(m2 - nm);
            se = se*f1 + se2*f2;
            a0 = a0*f1 + q0*f2; a1 = a1*f1 + q1*f2; a2 = a2*f1 + q2*f2;
            m = nm;
        }
        float inv = 1.f / (se + 1e-16f);
        float4 sk = skip4[n];
        float o0 = a0*inv + sk.x;
        float o1 = a1*inv + sk.y;
        float o2 = a2*inv + sk.z;
        // MLP 5->16->32->1 (pad rows unused); 32 cols split 4 per sub-lane
        float h1v[16];
        #pragma unroll
        for (int k2 = 0; k2 < 16; k2++)
            h1v[k2] = fmaxf(o0*W1[k2] + o1*W1[16+k2] + o2*W1[32+k2] + b1[k2], 0.f);
        float racc = 0.f;
        #pragma unroll
        for (int jj = 0; jj < 4; jj++) {
            int jc = sub*4 + jj;
            float t = b2[jc];
            #pragma unroll
            for (int k2 = 0; k2 < 16; k2++) t = fmaf(h1v[k2], W2[k2*32 + jc], t);
            racc = fmaf(fmaxf(t, 0.f), W3[jc], racc);
        }
        racc += __shfl_xor(racc, 1);
        racc += __shfl_xor(racc, 2);
        racc += __shfl_xor(racc, 4);
        __syncthreads();   // redf reuse boundary
        if (sub == 0) {
            float resv = racc + b3[0];
            outp[n] = resv * maskp[n];
            redf[j] = resv;
        }
        __syncthreads();
        if (tid == 0) {
            float s = 0.f;
            for (int q2 = 0; q2 < DPB; q2++) s += redf[q2];
            vpart[bid] = s;
        }
    }
    gbar(bar, NB * 17);

    if (bid == 0 && tid == 0) {
        float s = 0.f;
        for (int b = 0; b < NB; b++) s += vpart[b];
        outp[NN] = cW[0] * (s / (float)NN) + cb[0];
    }
}

// ---------------------------------------------------------------------------
extern "C" void kernel_launch(void* const* d_in, const int* in_sizes, int n_in,
                              void* d_out, int out_size, void* d_ws, size_t ws_size,
                              hipStream_t stream)
{
    const float* x    = (const float*)d_in[0];
    const int*   ei   = (const int*)  d_in[1];
    const float* mask = (const float*)d_in[2];
    const float* gW0  = (const float*)d_in[3];
    const float* gW   = (const float*)d_in[4];
    const float* atts = (const float*)d_in[5];
    const float* attd = (const float*)d_in[6];
    const float* gbias= (const float*)d_in[7];
    const float* mWq = (const float*)d_in[8];  const float* mbq = (const float*)d_in[9];
    const float* mWk = (const float*)d_in[10]; const float* mbk = (const float*)d_in[11];
    const float* mWv = (const float*)d_in[12]; const float* mbv = (const float*)d_in[13];
    const float* mWo = (const float*)d_in[14]; const float* mbo = (const float*)d_in[15];
    const float* tWq = (const float*)d_in[16]; const float* tbq = (const float*)d_in[17];
    const float* tWk = (const float*)d_in[18]; const float* tbk = (const float*)d_in[19];
    const float* tWv = (const float*)d_in[20]; const float* tbv = (const float*)d_in[21];
    const float* tWs = (const float*)d_in[22]; const float* tbs = (const float*)d_in[23];
    const float* W1  = (const float*)d_in[24]; const float* b1  = (const float*)d_in[25];
    const float* W2  = (const float*)d_in[26]; const float* b2  = (const float*)d_in[27];
    const float* W3  = (const float*)d_in[28]; const float* b3  = (const float*)d_in[29];
    const float* cW  = (const float*)d_in[30]; const float* cb  = (const float*)d_in[31];

    // zero the barrier counter + edge-count array every call (graph-safe)
    hipMemsetAsync(d_ws, 0, WS_MEMSET_BYTES, stream);

    k_fused<<<NB, BT, 0, stream>>>(x, ei, mask, gW0, gW, atts, attd, gbias,
                                   mWq, mbq, mWk, mbk, mWv, mbv, mWo, mbo,
                                   tWq, tbq, tWk, tbk, tWv, tbv, tWs, tbs,
                                   W1, b1, W2, b2, W3, b3, cW, cb,
                                   (char*)d_ws, (float*)d_out);
}